// Round 3
// baseline (2278.073 us; speedup 1.0000x reference)
//
#include <hip/hip_runtime.h>
#include <math.h>

// ---------------------------------------------------------------------------
// RNN_48558900248904: masked 2-layer alternating-parity tanh RNN, B=8192,
// T=200, H=256. Round 3: NT=3 (48 samples/WG, 171 WGs) to cut aggregate
// L2 weight streaming 1.5x and amortize per-phase overheads. 2 barriers/step,
// hreg dual-use (h0 B-frags read once in P2, reused as next P1 hh operand).
// xcat stride 176->168 shorts (odd 16B-quad stride: conflict-free).
// ---------------------------------------------------------------------------

typedef __attribute__((ext_vector_type(8))) short bf16x8;   // 8 bf16 (4 VGPRs)
typedef __attribute__((ext_vector_type(8))) short s16x8;    // 16B store
typedef __attribute__((ext_vector_type(4))) short s16x4;    // 8B store
typedef __attribute__((ext_vector_type(4))) float f32x4;

#define MFMA(a, b, c) __builtin_amdgcn_mfma_f32_16x16x32_bf16((a), (b), (c), 0, 0, 0)

#define T_  200
#define NT  3                             // sample tiles (16 each) per WG
#define NSAMP 48                          // NT*16

// ws layout (units: shorts unless noted)
#define WLP_OFF   0                       // Wl packed: 16mt x 5kk x 64lane x 8e
#define WIHP_OFF  40960                   // 4 mats x 65536  ([p][l]-ish flat)
#define WHHP_OFF  (40960 + 262144)
#define BSUM_BYTE_OFF ((40960 + 262144 + 262144) * 2)   // then [2][2][256] f32

// LDS layout (shorts)
#define XCS 168                           // xcat row stride: 21 quads (odd mod 8)
#define HS  264                           // h/xproj row stride: 33 quads (1 mod 8)
#define SM_XCAT 0                         // [48][168] = 8064
#define SM_XPJ  (48 * 168)                // [48][264] = 12672 each
#define SM_H0   (SM_XPJ + 48 * 264)
#define SM_H1A  (SM_H0 + 48 * 264)
#define SM_H1B  (SM_H1A + 48 * 264)
#define SM_TOT  (SM_H1B + 48 * 264)      // 58752 shorts = 117504 B

__device__ __forceinline__ short f2bf(float f) {
    unsigned u = __float_as_uint(f);
    u += 0x7fffu + ((u >> 16) & 1u);      // RNE
    return (short)(u >> 16);
}
__device__ __forceinline__ float bf2f(short s) {
    return __uint_as_float(((unsigned)(unsigned short)s) << 16);
}
__device__ __forceinline__ float tanh_fast(float x) {
    float e = exp2f(x * 2.88539008f);
    return 1.0f - 2.0f * __builtin_amdgcn_rcpf(e + 1.0f);
}

// ---------------------------------------------------------------------------
__global__ void prep_kernel(const float* __restrict__ Wl,
                            const float* __restrict__ Wih,
                            const float* __restrict__ Whh,
                            const float* __restrict__ bih,
                            const float* __restrict__ bhh,
                            short* __restrict__ wsS,
                            float* __restrict__ bsum) {
    int tid = blockIdx.x * 256 + threadIdx.x;
    if (tid < 5120) {                       // Wl pack (K padded 136 -> 160)
        int mt = tid / 320, rem = tid % 320;
        int kk = rem / 64, lane = rem % 64;
        int o = mt * 16 + (lane & 15);
        int kb = kk * 32 + (lane >> 4) * 8;
        short* dst = wsS + WLP_OFF + tid * 8;
#pragma unroll
        for (int e = 0; e < 8; e++) {
            int k = kb + e;
            dst[e] = f2bf((k < 136) ? Wl[o * 136 + k] : 0.0f);
        }
    } else if (tid < 5120 + 32768) {        // Wih pack
        int jj = tid - 5120;
        int mat = jj / 8192, rem = jj % 8192;
        int lane = rem & 63, kk = (rem >> 6) & 7, mt = rem >> 9;
        int o = mt * 16 + (lane & 15);
        int kb = kk * 32 + (lane >> 4) * 8;
        const float* src = Wih + (mat * 256 + o) * 256;
        short* dst = wsS + WIHP_OFF + mat * 65536 + rem * 8;
#pragma unroll
        for (int e = 0; e < 8; e++) dst[e] = f2bf(src[kb + e]);
    } else if (tid < 5120 + 65536) {        // Whh pack
        int jj = tid - 37888;
        int mat = jj / 8192, rem = jj % 8192;
        int lane = rem & 63, kk = (rem >> 6) & 7, mt = rem >> 9;
        int o = mt * 16 + (lane & 15);
        int kb = kk * 32 + (lane >> 4) * 8;
        const float* src = Whh + (mat * 256 + o) * 256;
        short* dst = wsS + WHHP_OFF + mat * 65536 + rem * 8;
#pragma unroll
        for (int e = 0; e < 8; e++) dst[e] = f2bf(src[kb + e]);
    } else if (tid < 5120 + 65536 + 1024) { // bsum = bih + bhh
        int j = tid - 70656;
        bsum[j] = bih[j] + bhh[j];
    }
}

// ---------------------------------------------------------------------------
// Gather for 48 samples: threads 0..383 = (sample, feat, half16) -> 16 emb
// floats; threads 384..479 = (sample, half8) -> 4 dense floats.
struct GReg { f32x4 e0, e1, e2, e3, dv; };

__device__ __forceinline__ void gather_load(GReg& g, const float* __restrict__ dense,
                                            const int* __restrict__ sparse,
                                            const float* __restrict__ emb,
                                            int b0, int tt, int tid) {
    if (tid < 384) {
        int gs = tid >> 3, gf = (tid >> 1) & 3, gh = tid & 1;
        int sg = min(b0 + gs, 8191);
        int ix = sparse[sg * (T_ * 4) + tt * 4 + gf];
        const float* ep = emb + gf * 32000 + ix * 32 + gh * 16;
        g.e0 = *(const f32x4*)ep;
        g.e1 = *(const f32x4*)(ep + 4);
        g.e2 = *(const f32x4*)(ep + 8);
        g.e3 = *(const f32x4*)(ep + 12);
    } else if (tid < 480) {
        int t2 = tid - 384;
        int s = t2 >> 1, half = t2 & 1;
        int sg = min(b0 + s, 8191);
        g.dv = *(const f32x4*)(dense + sg * (T_ * 8) + tt * 8 + half * 4);
    }
}
__device__ __forceinline__ void gather_commit(const GReg& g, short* __restrict__ buf, int tid) {
    if (tid < 384) {
        int gs = tid >> 3, gf = (tid >> 1) & 3, gh = tid & 1;
        s16x8 w0, w1;
#pragma unroll
        for (int r = 0; r < 4; r++) {
            w0[r]     = f2bf(g.e0[r]); w0[r + 4] = f2bf(g.e1[r]);
            w1[r]     = f2bf(g.e2[r]); w1[r + 4] = f2bf(g.e3[r]);
        }
        int off = gs * XCS + 8 + gf * 32 + gh * 16;
        *(s16x8*)(buf + off) = w0;
        *(s16x8*)(buf + off + 8) = w1;
    } else if (tid < 480) {
        int t2 = tid - 384;
        int s = t2 >> 1, half = t2 & 1;
        s16x4 wd;
#pragma unroll
        for (int r = 0; r < 4; r++) wd[r] = f2bf(g.dv[r]);
        *(s16x4*)(buf + s * XCS + half * 4) = wd;
    }
}

// xproj = relu(Wl x xcat + bl) -> xpj
__device__ __forceinline__ void phaseA(const short* __restrict__ xcat,
                                       short* __restrict__ xpj,
                                       const short* __restrict__ wsS,
                                       const f32x4* bl_r,
                                       int lane, int lrow, int lgrp, int wid) {
    f32x4 xacc[2][NT];
#pragma unroll
    for (int mt = 0; mt < 2; mt++)
#pragma unroll
        for (int nt = 0; nt < NT; nt++) xacc[mt][nt] = bl_r[mt];
#pragma unroll
    for (int kk = 0; kk < 5; kk++) {
        bf16x8 bxf[NT];
#pragma unroll
        for (int nt = 0; nt < NT; nt++)
            bxf[nt] = *(const bf16x8*)(xcat + (nt * 16 + lrow) * XCS + kk * 32 + lgrp * 8);
#pragma unroll
        for (int mt = 0; mt < 2; mt++) {
            bf16x8 af = *(const bf16x8*)(wsS + WLP_OFF + (((wid * 2 + mt) * 5 + kk) * 64 + lane) * 8);
#pragma unroll
            for (int nt = 0; nt < NT; nt++) xacc[mt][nt] = MFMA(af, bxf[nt], xacc[mt][nt]);
        }
    }
#pragma unroll
    for (int mt = 0; mt < 2; mt++) {
        int o0 = wid * 32 + mt * 16 + lgrp * 4;
#pragma unroll
        for (int nt = 0; nt < NT; nt++) {
            s16x4 w;
#pragma unroll
            for (int r = 0; r < 4; r++) w[r] = f2bf(fmaxf(xacc[mt][nt][r], 0.0f));
            *(s16x4*)(xpj + (nt * 16 + lrow) * HS + o0) = w;
        }
    }
}

// ---------------------------------------------------------------------------
__global__ __launch_bounds__(512, 2) void rnn_kernel(
    const float* __restrict__ dense, const int* __restrict__ sparse,
    const int* __restrict__ lengths, const float* __restrict__ emb,
    const float* __restrict__ bl, const float* __restrict__ Wout,
    const float* __restrict__ bout, const short* __restrict__ wsS,
    const float* __restrict__ bsum, float* __restrict__ out) {
    __shared__ alignas(16) short sm[SM_TOT];
    short* xcat = sm + SM_XCAT;
    short* xpj  = sm + SM_XPJ;
    short* h0p  = sm + SM_H0;
    short* h1a  = sm + SM_H1A;
    short* h1b  = sm + SM_H1B;

    const int tid  = threadIdx.x;
    const int wid  = tid >> 6;
    const int lane = tid & 63;
    const int lrow = lane & 15;
    const int lgrp = lane >> 4;
    const int b0   = blockIdx.x * NSAMP;

    for (int i = tid; i < SM_TOT; i += 512) sm[i] = 0;

    int lenr[NT];
#pragma unroll
    for (int nt = 0; nt < NT; nt++)
        lenr[nt] = lengths[min(b0 + nt * 16 + lrow, 8191)];

    // Bias preload into registers (constant across steps).
    f32x4 bl_r[2], bs00[2], bs01[2], bs10[2], bs11[2];
#pragma unroll
    for (int mt = 0; mt < 2; mt++) {
        int off = wid * 32 + mt * 16 + lgrp * 4;
        bl_r[mt] = *(const f32x4*)(bl + off);
        bs00[mt] = *(const f32x4*)(bsum + 0 * 256 + off);
        bs01[mt] = *(const f32x4*)(bsum + 1 * 256 + off);
        bs10[mt] = *(const f32x4*)(bsum + 2 * 256 + off);
        bs11[mt] = *(const f32x4*)(bsum + 3 * 256 + off);
    }

    __syncthreads();
    { GReg g0; gather_load(g0, dense, sparse, emb, b0, 0, tid); gather_commit(g0, xcat, tid); }
    __syncthreads();
    phaseA(xcat, xpj, wsS, bl_r, lane, lrow, lgrp, wid);   // xproj(0)

    bf16x8 hreg0[NT][8];           // B-frags of h0 (h0(-1) = 0)
#pragma unroll
    for (int nt = 0; nt < NT; nt++)
#pragma unroll
        for (int kk = 0; kk < 8; kk++) {
            bf16x8 z;
#pragma unroll
            for (int e = 0; e < 8; e++) z[e] = 0;
            hreg0[nt][kk] = z;
        }
    __syncthreads();               // xpj(0) visible

    for (int t = 0; t < T_; t++) {
        const int p = t & 1;
        const bool hasNext = (t + 1 < T_);
        GReg g;
        if (hasNext) gather_load(g, dense, sparse, emb, b0, t + 1, tid);

        // ================= P1: layer0(t) =================
        {
            f32x4 acc[2][NT];
#pragma unroll
            for (int mt = 0; mt < 2; mt++) {
                f32x4 bi = p ? bs01[mt] : bs00[mt];
#pragma unroll
                for (int nt = 0; nt < NT; nt++) acc[mt][nt] = bi;
            }
            const short* Aih = wsS + WIHP_OFF + p * 65536;
            const short* Ahh = wsS + WHHP_OFF + p * 65536;
#pragma unroll
            for (int kk = 0; kk < 8; kk++) {       // ih: B from xpj (LDS)
                bf16x8 bf[NT];
#pragma unroll
                for (int nt = 0; nt < NT; nt++)
                    bf[nt] = *(const bf16x8*)(xpj + (nt * 16 + lrow) * HS + kk * 32 + lgrp * 8);
#pragma unroll
                for (int mt = 0; mt < 2; mt++) {
                    bf16x8 af = *(const bf16x8*)(Aih + (((wid * 2 + mt) * 8 + kk) * 64 + lane) * 8);
#pragma unroll
                    for (int nt = 0; nt < NT; nt++) acc[mt][nt] = MFMA(af, bf[nt], acc[mt][nt]);
                }
            }
#pragma unroll
            for (int kk = 0; kk < 8; kk++) {       // hh: B from hreg0 (regs)
#pragma unroll
                for (int mt = 0; mt < 2; mt++) {
                    bf16x8 af = *(const bf16x8*)(Ahh + (((wid * 2 + mt) * 8 + kk) * 64 + lane) * 8);
#pragma unroll
                    for (int nt = 0; nt < NT; nt++) acc[mt][nt] = MFMA(af, hreg0[nt][kk], acc[mt][nt]);
                }
            }
#pragma unroll
            for (int mt = 0; mt < 2; mt++) {       // in-place predicated write
                int o0 = wid * 32 + mt * 16 + lgrp * 4;
#pragma unroll
                for (int nt = 0; nt < NT; nt++) {
                    s16x4 w;
#pragma unroll
                    for (int r = 0; r < 4; r++) w[r] = f2bf(tanh_fast(acc[mt][nt][r]));
                    if (t < lenr[nt])
                        *(s16x4*)(h0p + (nt * 16 + lrow) * HS + o0) = w;
                }
            }
        }
        if (hasNext) gather_commit(g, xcat, tid);
        __syncthreads();   // h0 updated; xcat(t+1) committed

        // ================= P2: layer1(t) + xproj(t+1) =================
        {
            const short* h1r = p ? h1b : h1a;
            short* h1w = p ? h1a : h1b;

            f32x4 acc[2][NT];
#pragma unroll
            for (int mt = 0; mt < 2; mt++) {
                f32x4 bi = p ? bs11[mt] : bs10[mt];
#pragma unroll
                for (int nt = 0; nt < NT; nt++) acc[mt][nt] = bi;
            }
            const short* Aih = wsS + WIHP_OFF + (2 + p) * 65536;
            const short* Ahh = wsS + WHHP_OFF + (2 + p) * 65536;
#pragma unroll
            for (int kk = 0; kk < 8; kk++) {       // ih: B = fresh h0 frags
#pragma unroll
                for (int nt = 0; nt < NT; nt++)    // (also next P1's hh operand)
                    hreg0[nt][kk] = *(const bf16x8*)(h0p + (nt * 16 + lrow) * HS + kk * 32 + lgrp * 8);
#pragma unroll
                for (int mt = 0; mt < 2; mt++) {
                    bf16x8 af = *(const bf16x8*)(Aih + (((wid * 2 + mt) * 8 + kk) * 64 + lane) * 8);
#pragma unroll
                    for (int nt = 0; nt < NT; nt++) acc[mt][nt] = MFMA(af, hreg0[nt][kk], acc[mt][nt]);
                }
            }
#pragma unroll
            for (int kk = 0; kk < 8; kk++) {       // hh: B from h1r (LDS)
                bf16x8 bhf[NT];
#pragma unroll
                for (int nt = 0; nt < NT; nt++)
                    bhf[nt] = *(const bf16x8*)(h1r + (nt * 16 + lrow) * HS + kk * 32 + lgrp * 8);
#pragma unroll
                for (int mt = 0; mt < 2; mt++) {
                    bf16x8 af = *(const bf16x8*)(Ahh + (((wid * 2 + mt) * 8 + kk) * 64 + lane) * 8);
#pragma unroll
                    for (int nt = 0; nt < NT; nt++) acc[mt][nt] = MFMA(af, bhf[nt], acc[mt][nt]);
                }
            }

            if (hasNext)   // independent GEMM: interleaves with layer1 above
                phaseA(xcat, xpj, wsS, bl_r, lane, lrow, lgrp, wid);

            // h1 write: ping-pong with select-copy freeze
#pragma unroll
            for (int mt = 0; mt < 2; mt++) {
                int o0 = wid * 32 + mt * 16 + lgrp * 4;
#pragma unroll
                for (int nt = 0; nt < NT; nt++) {
                    int roff = (nt * 16 + lrow) * HS + o0;
                    s16x4 oldv = *(const s16x4*)(h1r + roff);
                    s16x4 w;
#pragma unroll
                    for (int r = 0; r < 4; r++) w[r] = f2bf(tanh_fast(acc[mt][nt][r]));
                    *(s16x4*)(h1w + roff) = (t < lenr[nt]) ? w : oldv;
                }
            }
        }
        __syncthreads();   // h1(t), xpj(t+1) visible
    }

    // ---- epilogue: out = sigmoid(h1 . Wout + bout); final h1 = h1a (T even)
    float* red = (float*)(sm + SM_XPJ);
    if (tid < NSAMP * 8) {
        int s = tid >> 3, part = tid & 7;
        const short* hr = h1a + s * HS + part * 32;
        float sum = 0.0f;
#pragma unroll
        for (int k = 0; k < 32; k++) sum += bf2f(hr[k]) * Wout[part * 32 + k];
        red[s * 8 + part] = sum;
    }
    __syncthreads();
    if (tid < NSAMP && b0 + tid < 8192) {
        float x = bout[0];
#pragma unroll
        for (int i = 0; i < 8; i++) x += red[tid * 8 + i];
        float e = exp2f(x * 1.44269504f);
        out[b0 + tid] = 1.0f - __builtin_amdgcn_rcpf(1.0f + e);
    }
}

// ---------------------------------------------------------------------------
extern "C" void kernel_launch(void* const* d_in, const int* in_sizes, int n_in,
                              void* d_out, int out_size, void* d_ws, size_t ws_size,
                              hipStream_t stream) {
    const float* dense   = (const float*)d_in[0];
    const int*   sparse  = (const int*)d_in[1];
    const int*   lengths = (const int*)d_in[2];
    const float* emb     = (const float*)d_in[3];
    const float* Wl      = (const float*)d_in[4];
    const float* bl      = (const float*)d_in[5];
    const float* Wih     = (const float*)d_in[6];
    const float* Whh     = (const float*)d_in[7];
    const float* bih     = (const float*)d_in[8];
    const float* bhh     = (const float*)d_in[9];
    const float* Wout    = (const float*)d_in[10];
    const float* bout    = (const float*)d_in[11];

    short* wsS  = (short*)d_ws;
    float* bsum = (float*)((char*)d_ws + BSUM_BYTE_OFF);

    prep_kernel<<<280, 256, 0, stream>>>(Wl, Wih, Whh, bih, bhh, wsS, bsum);
    rnn_kernel<<<171, 512, 0, stream>>>(dense, sparse, lengths, emb, bl, Wout, bout,
                                        wsS, bsum, (float*)d_out);
}

// Round 4
// 1420.676 us; speedup vs baseline: 1.6035x; 1.6035x over previous
//
#include <hip/hip_runtime.h>
#include <math.h>

// ---------------------------------------------------------------------------
// RNN_48558900248904: masked 2-layer alternating-parity tanh RNN, B=8192,
// T=200, H=256. Round 4: back to NT=2 / 256 WGs (R3's 171-WG grid idled 85
// CUs and spilled). New: full-phase weight prefetch into registers (batch all
// A-frag global loads before the MFMA chains -> deep outstanding VMEM instead
// of per-kk latency serialization); biases moved to LDS (frees ~40 VGPRs).
// ---------------------------------------------------------------------------

typedef __attribute__((ext_vector_type(8))) short bf16x8;   // 8 bf16 (4 VGPRs)
typedef __attribute__((ext_vector_type(4))) short s16x4;    // 8B store
typedef __attribute__((ext_vector_type(4))) float f32x4;

#define MFMA(a, b, c) __builtin_amdgcn_mfma_f32_16x16x32_bf16((a), (b), (c), 0, 0, 0)

#define T_  200

// ws layout (units: shorts unless noted)
#define WLP_OFF   0                       // Wl packed: 16mt x 5kk x 64lane x 8e
#define WIHP_OFF  40960                   // 4 mats x 65536  ([l][p] flat)
#define WHHP_OFF  (40960 + 262144)
#define BSUM_BYTE_OFF ((40960 + 262144 + 262144) * 2)   // then [2][2][256] f32

// LDS layout (shorts)
#define XCS 168                           // xcat row stride (conflict-free)
#define HS  264                           // h/xproj row stride
#define SM_XCAT 0                         // [32][168] = 5376
#define SM_XPJ  5376                      // [32][264] = 8448 each
#define SM_H0   (SM_XPJ + 8448)
#define SM_H1A  (SM_H0 + 8448)
#define SM_H1B  (SM_H1A + 8448)
#define SM_BIAS (SM_H1B + 8448)          // 1280 f32 = 2560 shorts (16B aligned)
#define SM_TOT  (SM_BIAS + 2560)         // 41984 shorts = 83968 B

__device__ __forceinline__ short f2bf(float f) {
    unsigned u = __float_as_uint(f);
    u += 0x7fffu + ((u >> 16) & 1u);      // RNE
    return (short)(u >> 16);
}
__device__ __forceinline__ float bf2f(short s) {
    return __uint_as_float(((unsigned)(unsigned short)s) << 16);
}
__device__ __forceinline__ float tanh_fast(float x) {
    float e = exp2f(x * 2.88539008f);
    return 1.0f - 2.0f * __builtin_amdgcn_rcpf(e + 1.0f);
}

// ---------------------------------------------------------------------------
__global__ void prep_kernel(const float* __restrict__ Wl,
                            const float* __restrict__ Wih,
                            const float* __restrict__ Whh,
                            const float* __restrict__ bih,
                            const float* __restrict__ bhh,
                            short* __restrict__ wsS,
                            float* __restrict__ bsum) {
    int tid = blockIdx.x * 256 + threadIdx.x;
    if (tid < 5120) {                       // Wl pack (K padded 136 -> 160)
        int mt = tid / 320, rem = tid % 320;
        int kk = rem / 64, lane = rem % 64;
        int o = mt * 16 + (lane & 15);
        int kb = kk * 32 + (lane >> 4) * 8;
        short* dst = wsS + WLP_OFF + tid * 8;
#pragma unroll
        for (int e = 0; e < 8; e++) {
            int k = kb + e;
            dst[e] = f2bf((k < 136) ? Wl[o * 136 + k] : 0.0f);
        }
    } else if (tid < 5120 + 32768) {        // Wih pack
        int jj = tid - 5120;
        int mat = jj / 8192, rem = jj % 8192;
        int lane = rem & 63, kk = (rem >> 6) & 7, mt = rem >> 9;
        int o = mt * 16 + (lane & 15);
        int kb = kk * 32 + (lane >> 4) * 8;
        const float* src = Wih + (mat * 256 + o) * 256;
        short* dst = wsS + WIHP_OFF + mat * 65536 + rem * 8;
#pragma unroll
        for (int e = 0; e < 8; e++) dst[e] = f2bf(src[kb + e]);
    } else if (tid < 5120 + 65536) {        // Whh pack
        int jj = tid - 37888;
        int mat = jj / 8192, rem = jj % 8192;
        int lane = rem & 63, kk = (rem >> 6) & 7, mt = rem >> 9;
        int o = mt * 16 + (lane & 15);
        int kb = kk * 32 + (lane >> 4) * 8;
        const float* src = Whh + (mat * 256 + o) * 256;
        short* dst = wsS + WHHP_OFF + mat * 65536 + rem * 8;
#pragma unroll
        for (int e = 0; e < 8; e++) dst[e] = f2bf(src[kb + e]);
    } else if (tid < 5120 + 65536 + 1024) { // bsum = bih + bhh
        int j = tid - 70656;
        bsum[j] = bih[j] + bhh[j];
    }
}

// ---------------------------------------------------------------------------
struct GReg { f32x4 e0, e1, dv; };

__device__ __forceinline__ void gather_load(GReg& g, const float* __restrict__ dense,
                                            const int* __restrict__ sparse,
                                            const float* __restrict__ emb,
                                            int b0, int tt, int tid) {
    int gs = tid >> 4, gf = (tid >> 2) & 3, gq = tid & 3;
    int ix = sparse[(b0 + gs) * (T_ * 4) + tt * 4 + gf];
    const float* ep = emb + gf * 32000 + ix * 32 + gq * 8;
    g.e0 = *(const f32x4*)ep;
    g.e1 = *(const f32x4*)(ep + 4);
    if (tid < 64)
        g.dv = *(const f32x4*)(dense + (b0 + (tid >> 1)) * (T_ * 8) + tt * 8 + (tid & 1) * 4);
}
__device__ __forceinline__ void gather_commit(const GReg& g, short* __restrict__ buf, int tid) {
    int gs = tid >> 4, gf = (tid >> 2) & 3, gq = tid & 3;
    s16x4 w0, w1;
#pragma unroll
    for (int r = 0; r < 4; r++) { w0[r] = f2bf(g.e0[r]); w1[r] = f2bf(g.e1[r]); }
    int off = gs * XCS + 8 + gf * 32 + gq * 8;
    *(s16x4*)(buf + off) = w0;
    *(s16x4*)(buf + off + 4) = w1;
    if (tid < 64) {
        s16x4 wd;
#pragma unroll
        for (int r = 0; r < 4; r++) wd[r] = f2bf(g.dv[r]);
        *(s16x4*)(buf + (tid >> 1) * XCS + (tid & 1) * 4) = wd;
    }
}

// xproj = relu(Wl x xcat + bl) -> xpj   (wl prefetched into regs)
__device__ __forceinline__ void phaseA(const short* __restrict__ xcat,
                                       short* __restrict__ xpj,
                                       const short* __restrict__ wsS,
                                       const float* __restrict__ blS,
                                       int lane, int lrow, int lgrp, int wid) {
    bf16x8 wl[2][5];
#pragma unroll
    for (int kk = 0; kk < 5; kk++)
#pragma unroll
        for (int mt = 0; mt < 2; mt++)
            wl[mt][kk] = *(const bf16x8*)(wsS + WLP_OFF + (((wid * 2 + mt) * 5 + kk) * 64 + lane) * 8);
    f32x4 xacc[2][2];
#pragma unroll
    for (int mt = 0; mt < 2; mt++) {
        f32x4 bi = *(const f32x4*)(blS + wid * 32 + mt * 16 + lgrp * 4);
        xacc[mt][0] = bi; xacc[mt][1] = bi;
    }
#pragma unroll
    for (int kk = 0; kk < 5; kk++) {
        bf16x8 bxf[2];
#pragma unroll
        for (int nt = 0; nt < 2; nt++)
            bxf[nt] = *(const bf16x8*)(xcat + (nt * 16 + lrow) * XCS + kk * 32 + lgrp * 8);
#pragma unroll
        for (int mt = 0; mt < 2; mt++)
#pragma unroll
            for (int nt = 0; nt < 2; nt++) xacc[mt][nt] = MFMA(wl[mt][kk], bxf[nt], xacc[mt][nt]);
    }
#pragma unroll
    for (int mt = 0; mt < 2; mt++) {
        int o0 = wid * 32 + mt * 16 + lgrp * 4;
#pragma unroll
        for (int nt = 0; nt < 2; nt++) {
            s16x4 w;
#pragma unroll
            for (int r = 0; r < 4; r++) w[r] = f2bf(fmaxf(xacc[mt][nt][r], 0.0f));
            *(s16x4*)(xpj + (nt * 16 + lrow) * HS + o0) = w;
        }
    }
}

// ---------------------------------------------------------------------------
__global__ __launch_bounds__(512, 2) void rnn_kernel(
    const float* __restrict__ dense, const int* __restrict__ sparse,
    const int* __restrict__ lengths, const float* __restrict__ emb,
    const float* __restrict__ bl, const float* __restrict__ Wout,
    const float* __restrict__ bout, const short* __restrict__ wsS,
    const float* __restrict__ bsum, float* __restrict__ out) {
    __shared__ alignas(16) short sm[SM_TOT];
    short* xcat = sm + SM_XCAT;
    short* xpj  = sm + SM_XPJ;
    short* h0p  = sm + SM_H0;
    short* h1a  = sm + SM_H1A;
    short* h1b  = sm + SM_H1B;
    float* blS  = (float*)(sm + SM_BIAS);   // [0,256)=bl, [256+q*256..) q=l*2+p

    const int tid  = threadIdx.x;
    const int wid  = tid >> 6;
    const int lane = tid & 63;
    const int lrow = lane & 15;
    const int lgrp = lane >> 4;
    const int b0   = blockIdx.x * 32;

    for (int i = tid; i < SM_BIAS; i += 512) sm[i] = 0;
    for (int i = tid; i < 1280; i += 512)
        blS[i] = (i < 256) ? bl[i] : bsum[i - 256];

    const int len0 = lengths[b0 + lrow];
    const int len1 = lengths[b0 + 16 + lrow];

    __syncthreads();
    { GReg g0; gather_load(g0, dense, sparse, emb, b0, 0, tid); gather_commit(g0, xcat, tid); }
    __syncthreads();
    phaseA(xcat, xpj, wsS, blS, lane, lrow, lgrp, wid);   // xproj(0)

    bf16x8 hreg0[2][8];            // B-frags of h0 (h0(-1) = 0)
#pragma unroll
    for (int nt = 0; nt < 2; nt++)
#pragma unroll
        for (int kk = 0; kk < 8; kk++) {
            bf16x8 z;
#pragma unroll
            for (int e = 0; e < 8; e++) z[e] = 0;
            hreg0[nt][kk] = z;
        }
    __syncthreads();               // xpj(0) visible

    for (int t = 0; t < T_; t++) {
        const int p = t & 1;
        const bool hasNext = (t + 1 < T_);
        GReg g;
        if (hasNext) gather_load(g, dense, sparse, emb, b0, t + 1, tid);

        // ================= P1: layer0(t) =================
        {
            const short* Aih = wsS + WIHP_OFF + p * 65536;
            const short* Ahh = wsS + WHHP_OFF + p * 65536;
            bf16x8 wih[2][8], whh[2][8];     // full-phase weight prefetch
#pragma unroll
            for (int kk = 0; kk < 8; kk++)
#pragma unroll
                for (int mt = 0; mt < 2; mt++)
                    wih[mt][kk] = *(const bf16x8*)(Aih + (((wid * 2 + mt) * 8 + kk) * 64 + lane) * 8);
#pragma unroll
            for (int kk = 0; kk < 8; kk++)
#pragma unroll
                for (int mt = 0; mt < 2; mt++)
                    whh[mt][kk] = *(const bf16x8*)(Ahh + (((wid * 2 + mt) * 8 + kk) * 64 + lane) * 8);

            f32x4 acc[2][2];
#pragma unroll
            for (int mt = 0; mt < 2; mt++) {
                f32x4 bi = *(const f32x4*)(blS + 256 + p * 256 + wid * 32 + mt * 16 + lgrp * 4);
                acc[mt][0] = bi; acc[mt][1] = bi;
            }
#pragma unroll
            for (int kk = 0; kk < 8; kk++) {       // ih: B from xpj (LDS)
                bf16x8 bf[2];
#pragma unroll
                for (int nt = 0; nt < 2; nt++)
                    bf[nt] = *(const bf16x8*)(xpj + (nt * 16 + lrow) * HS + kk * 32 + lgrp * 8);
#pragma unroll
                for (int mt = 0; mt < 2; mt++)
#pragma unroll
                    for (int nt = 0; nt < 2; nt++) acc[mt][nt] = MFMA(wih[mt][kk], bf[nt], acc[mt][nt]);
            }
#pragma unroll
            for (int kk = 0; kk < 8; kk++)         // hh: B from hreg0 (regs)
#pragma unroll
                for (int mt = 0; mt < 2; mt++)
#pragma unroll
                    for (int nt = 0; nt < 2; nt++) acc[mt][nt] = MFMA(whh[mt][kk], hreg0[nt][kk], acc[mt][nt]);

#pragma unroll
            for (int mt = 0; mt < 2; mt++) {       // in-place predicated write
                int o0 = wid * 32 + mt * 16 + lgrp * 4;
#pragma unroll
                for (int nt = 0; nt < 2; nt++) {
                    s16x4 w;
#pragma unroll
                    for (int r = 0; r < 4; r++) w[r] = f2bf(tanh_fast(acc[mt][nt][r]));
                    int len = nt ? len1 : len0;
                    if (t < len)
                        *(s16x4*)(h0p + (nt * 16 + lrow) * HS + o0) = w;
                }
            }
        }
        if (hasNext) gather_commit(g, xcat, tid);
        __syncthreads();   // h0 updated; xcat(t+1) committed

        // ================= P2: layer1(t) + xproj(t+1) =================
        {
            const short* h1r = p ? h1b : h1a;
            short* h1w = p ? h1a : h1b;
            const short* Aih = wsS + WIHP_OFF + (2 + p) * 65536;
            const short* Ahh = wsS + WHHP_OFF + (2 + p) * 65536;

            // fresh h0 B-frags: layer1 ih operand AND next P1's hh operand
#pragma unroll
            for (int nt = 0; nt < 2; nt++)
#pragma unroll
                for (int kk = 0; kk < 8; kk++)
                    hreg0[nt][kk] = *(const bf16x8*)(h0p + (nt * 16 + lrow) * HS + kk * 32 + lgrp * 8);

            bf16x8 wih[2][8], whh[2][8];     // full-phase weight prefetch
#pragma unroll
            for (int kk = 0; kk < 8; kk++)
#pragma unroll
                for (int mt = 0; mt < 2; mt++)
                    wih[mt][kk] = *(const bf16x8*)(Aih + (((wid * 2 + mt) * 8 + kk) * 64 + lane) * 8);
#pragma unroll
            for (int kk = 0; kk < 8; kk++)
#pragma unroll
                for (int mt = 0; mt < 2; mt++)
                    whh[mt][kk] = *(const bf16x8*)(Ahh + (((wid * 2 + mt) * 8 + kk) * 64 + lane) * 8);

            f32x4 acc[2][2];
#pragma unroll
            for (int mt = 0; mt < 2; mt++) {
                f32x4 bi = *(const f32x4*)(blS + 256 + (2 + p) * 256 + wid * 32 + mt * 16 + lgrp * 4);
                acc[mt][0] = bi; acc[mt][1] = bi;
            }
#pragma unroll
            for (int kk = 0; kk < 8; kk++)         // ih: B = hreg0
#pragma unroll
                for (int mt = 0; mt < 2; mt++)
#pragma unroll
                    for (int nt = 0; nt < 2; nt++) acc[mt][nt] = MFMA(wih[mt][kk], hreg0[nt][kk], acc[mt][nt]);
#pragma unroll
            for (int kk = 0; kk < 8; kk++) {       // hh: B from h1r (LDS)
                bf16x8 bhf[2];
#pragma unroll
                for (int nt = 0; nt < 2; nt++)
                    bhf[nt] = *(const bf16x8*)(h1r + (nt * 16 + lrow) * HS + kk * 32 + lgrp * 8);
#pragma unroll
                for (int mt = 0; mt < 2; mt++)
#pragma unroll
                    for (int nt = 0; nt < 2; nt++) acc[mt][nt] = MFMA(whh[mt][kk], bhf[nt], acc[mt][nt]);
            }

            if (hasNext)   // independent GEMM: interleaves with layer1 above
                phaseA(xcat, xpj, wsS, blS, lane, lrow, lgrp, wid);

            // h1 write: ping-pong with select-copy freeze
#pragma unroll
            for (int mt = 0; mt < 2; mt++) {
                int o0 = wid * 32 + mt * 16 + lgrp * 4;
#pragma unroll
                for (int nt = 0; nt < 2; nt++) {
                    int roff = (nt * 16 + lrow) * HS + o0;
                    s16x4 oldv = *(const s16x4*)(h1r + roff);
                    s16x4 w;
#pragma unroll
                    for (int r = 0; r < 4; r++) w[r] = f2bf(tanh_fast(acc[mt][nt][r]));
                    int len = nt ? len1 : len0;
                    *(s16x4*)(h1w + roff) = (t < len) ? w : oldv;
                }
            }
        }
        __syncthreads();   // h1(t), xpj(t+1) visible
    }

    // ---- epilogue: out = sigmoid(h1 . Wout + bout); final h1 = h1a (T even)
    float* red = (float*)(sm + SM_XPJ);
    if (tid < 256) {
        int s = tid >> 3, part = tid & 7;
        const short* hr = h1a + s * HS + part * 32;
        float sum = 0.0f;
#pragma unroll
        for (int k = 0; k < 32; k++) sum += bf2f(hr[k]) * Wout[part * 32 + k];
        red[s * 8 + part] = sum;
    }
    __syncthreads();
    if (tid < 32) {
        float x = bout[0];
#pragma unroll
        for (int i = 0; i < 8; i++) x += red[tid * 8 + i];
        float e = exp2f(x * 1.44269504f);
        out[b0 + tid] = 1.0f - __builtin_amdgcn_rcpf(1.0f + e);
    }
}

// ---------------------------------------------------------------------------
extern "C" void kernel_launch(void* const* d_in, const int* in_sizes, int n_in,
                              void* d_out, int out_size, void* d_ws, size_t ws_size,
                              hipStream_t stream) {
    const float* dense   = (const float*)d_in[0];
    const int*   sparse  = (const int*)d_in[1];
    const int*   lengths = (const int*)d_in[2];
    const float* emb     = (const float*)d_in[3];
    const float* Wl      = (const float*)d_in[4];
    const float* bl      = (const float*)d_in[5];
    const float* Wih     = (const float*)d_in[6];
    const float* Whh     = (const float*)d_in[7];
    const float* bih     = (const float*)d_in[8];
    const float* bhh     = (const float*)d_in[9];
    const float* Wout    = (const float*)d_in[10];
    const float* bout    = (const float*)d_in[11];

    short* wsS  = (short*)d_ws;
    float* bsum = (float*)((char*)d_ws + BSUM_BYTE_OFF);

    prep_kernel<<<280, 256, 0, stream>>>(Wl, Wih, Whh, bih, bhh, wsS, bsum);
    rnn_kernel<<<256, 512, 0, stream>>>(dense, sparse, lengths, emb, bl, Wout, bout,
                                        wsS, bsum, (float*)d_out);
}